// Round 1
// baseline (113.849 us; speedup 1.0000x reference)
//
#include <hip/hip_runtime.h>

#define BATCH 4
#define NCLS 2
#define VOX 1638400            // 64*160*160
#define VOX4 (VOX / 4)
#define BLOCKS_X 512
#define THREADS 256
#define NACC 19                // S0, A, n0, P[1..8], N[1..8]

// ---------------------------------------------------------------------------
// Kernel 1: per-(sample, block) partial reductions.
// partials layout: [(j*BATCH + b) * BLOCKS_X + blockIdx.x], j in [0,19)
// so kernel 2's lanes read coalesced along the block axis.
// ---------------------------------------------------------------------------
__global__ __launch_bounds__(THREADS) void blob_reduce_kernel(
    const float* __restrict__ x, const int* __restrict__ ml,
    float* __restrict__ partials)
{
    const int b = blockIdx.y;
    const float4* __restrict__ x0v = (const float4*)(x + (size_t)b * NCLS * VOX);
    const float4* __restrict__ x1v = (const float4*)(x + (size_t)b * NCLS * VOX + VOX);
    const int4*   __restrict__ mlv = (const int4*)(ml + (size_t)b * VOX);

    float acc[NACC];
#pragma unroll
    for (int j = 0; j < NACC; ++j) acc[j] = 0.f;

    const int stride = BLOCKS_X * THREADS;
    for (int i = blockIdx.x * THREADS + threadIdx.x; i < VOX4; i += stride) {
        float4 a0 = x0v[i];
        float4 a1 = x1v[i];
        int4   m  = mlv[i];
        float xs0[4] = {a0.x, a0.y, a0.z, a0.w};
        float xs1[4] = {a1.x, a1.y, a1.z, a1.w};
        int   ls[4]  = {m.x, m.y, m.z, m.w};
#pragma unroll
        for (int e = 0; e < 4; ++e) {
            // softmax over 2 classes: p0 = 1/(1+exp(x1-x0))
            float p0 = 1.0f / (1.0f + __expf(xs1[e] - xs0[e]));
            int L = ls[e];
            acc[0] += p0;                      // S0
            bool z = (L == 0);
            acc[1] += z ? p0 : 0.f;            // A
            acc[2] += z ? 1.f : 0.f;           // n0
#pragma unroll
            for (int l = 0; l < 8; ++l) {
                bool eq = (L == l + 1);
                acc[3 + l]  += eq ? p0 : 0.f;  // P_l
                acc[11 + l] += eq ? 1.f : 0.f; // N_l
            }
        }
    }

    // block reduce: wave shuffle (64 lanes) -> LDS across 4 waves
    __shared__ float red[4][NACC];
    const int lane = threadIdx.x & 63;
    const int wave = threadIdx.x >> 6;
#pragma unroll
    for (int j = 0; j < NACC; ++j) {
        float v = acc[j];
        for (int off = 32; off > 0; off >>= 1) v += __shfl_down(v, off, 64);
        if (lane == 0) red[wave][j] = v;
    }
    __syncthreads();
    if (threadIdx.x < NACC) {
        float s = red[0][threadIdx.x] + red[1][threadIdx.x] +
                  red[2][threadIdx.x] + red[3][threadIdx.x];
        partials[((size_t)threadIdx.x * BATCH + b) * BLOCKS_X + blockIdx.x] = s;
    }
}

// ---------------------------------------------------------------------------
// Kernel 2: reduce 512 partials per (j,b) in double, then closed-form loss.
// ---------------------------------------------------------------------------
__global__ __launch_bounds__(512) void blob_finalize_kernel(
    const float* __restrict__ partials, float* __restrict__ out)
{
    __shared__ double totals[NACC * BATCH];   // index p = j*BATCH + b
    const int lane = threadIdx.x & 63;
    const int wave = threadIdx.x >> 6;        // 8 waves

    for (int p = wave; p < NACC * BATCH; p += 8) {
        double s = 0.0;
#pragma unroll
        for (int i = 0; i < BLOCKS_X / 64; ++i)
            s += (double)partials[(size_t)p * BLOCKS_X + lane + i * 64];
        for (int off = 32; off > 0; off >>= 1) s += __shfl_down(s, off, 64);
        if (lane == 0) totals[p] = s;
    }
    __syncthreads();

    if (threadIdx.x == 0) {
        const double Vd = (double)VOX;
        const double TA = 0.3, TB = 0.7;
        double sum_main = 0.0, sum_blob = 0.0;
        for (int b = 0; b < BATCH; ++b) {
            const double S0 = totals[0 * BATCH + b];
            const double A  = totals[1 * BATCH + b];
            const double n0 = totals[2 * BATCH + b];
            // main Tversky, class 0
            {
                double tp = A, fp = S0 - A, fn = n0 - A;
                sum_main += tp / fmax(tp + TA * fp + TB * fn, 1e-8);
            }
            // main Tversky, class 1
            {
                double tp = (Vd - n0) - (S0 - A);
                double fp = (Vd - S0) - tp;
                double fn = (Vd - n0) - tp;
                sum_main += tp / fmax(tp + TA * fp + TB * fn, 1e-8);
            }
            for (int k = 0; k < 8; ++k) {
                const double P0 = totals[(3 + k) * BATCH + b];
                const double Nl = totals[(11 + k) * BATCH + b];
                const double P1 = Nl - P0;
                const double m  = Vd - n0 - Nl;  // voxels of OTHER blobs -> p=(.5,.5)
                // class 0: g = (L != lab)
                {
                    double tp = A + 0.5 * m;
                    double fp = P0;
                    double fn = (Vd - Nl) - tp;
                    sum_blob += tp / fmax(tp + TA * fp + TB * fn, 1e-8);
                }
                // class 1: g = (L == lab)
                {
                    double tp = P1;
                    double fp = (n0 - A) + 0.5 * m;
                    double fn = P0;
                    sum_blob += tp / fmax(tp + TA * fp + TB * fn, 1e-8);
                }
            }
        }
        // loss = MAIN_W*CRIT_W*main_loss + blob_loss
        //      = -(sum_main / (B*C)) - (0.25/(K*B)) * sum_blob
        out[0] = (float)(-(sum_main / 8.0 + sum_blob / 128.0));
    }
}

extern "C" void kernel_launch(void* const* d_in, const int* in_sizes, int n_in,
                              void* d_out, int out_size, void* d_ws, size_t ws_size,
                              hipStream_t stream) {
    const float* x  = (const float*)d_in[0];
    const int*   ml = (const int*)d_in[1];
    float* out      = (float*)d_out;
    float* partials = (float*)d_ws;   // NACC*BATCH*BLOCKS_X floats = 152 KiB

    dim3 grid(BLOCKS_X, BATCH);
    blob_reduce_kernel<<<grid, THREADS, 0, stream>>>(x, ml, partials);
    blob_finalize_kernel<<<1, 512, 0, stream>>>(partials, out);
}